// Round 1
// baseline (217.993 us; speedup 1.0000x reference)
//
#include <hip/hip_runtime.h>
#include <math.h>

#define B_ 8192
#define D_ 4096
#define K_ 64
#define EPSF 1e-8f
#define NSPLIT 4
#define LN2F 0.69314718056f

// ---------------- reduction helpers ----------------

__device__ __forceinline__ float wave_reduce_f(float v) {
#pragma unroll
  for (int o = 32; o > 0; o >>= 1) v += __shfl_down(v, o);
  return v;
}

// ---------------- kernels ----------------

__global__ void k_init(int* __restrict__ counts) {
  if (threadIdx.x < K_) counts[threadIdx.x] = 0;
}

// one wave per row; K_ == 64 == wavefront size, so one coalesced read + ballot
__global__ void k_labels(const float* __restrict__ probs, int* __restrict__ labels,
                         int* __restrict__ counts, int* __restrict__ rowlist) {
  int row = blockIdx.x * 4 + (threadIdx.x >> 6);
  int lane = threadIdx.x & 63;
  float p = probs[(size_t)row * K_ + lane];
  unsigned long long m = __ballot(p > 0.5f);
  if (lane == 0) {
    int k = __ffsll(m) - 1;
    if (k >= 0) {
      labels[row] = k;
      int pos = atomicAdd(&counts[k], 1);
      rowlist[k * B_ + pos] = row;
    }
  }
}

__device__ __forceinline__ float ent_log2(float p) {
  // -(p*log2(p) + q*log2(q)); caller multiplies by ln2
  p = fminf(fmaxf(p, 1e-8f), 0.99999999f);
  float q = 1.0f - p;
  return -(p * __log2f(p) + q * __log2f(fmaxf(q, 1e-45f)));
}

// fused binary entropy over both masks; per-block partials in double
__global__ void k_entropy(const float4* __restrict__ m1, const float4* __restrict__ m8,
                          double* __restrict__ entpart) {
  __shared__ float lds[8];
  const int N4 = B_ * D_ / 4;
  int tid = blockIdx.x * blockDim.x + threadIdx.x;
  int stride = gridDim.x * blockDim.x;
  float s1 = 0.f, s8 = 0.f;
  for (int i = tid; i < N4; i += stride) {
    float4 a = m1[i];
    float4 b = m8[i];
    s1 += ent_log2(a.x) + ent_log2(a.y) + ent_log2(a.z) + ent_log2(a.w);
    s8 += ent_log2(b.x) + ent_log2(b.y) + ent_log2(b.z) + ent_log2(b.w);
  }
  s1 = wave_reduce_f(s1);
  s8 = wave_reduce_f(s8);
  int wid = threadIdx.x >> 6;
  if ((threadIdx.x & 63) == 0) { lds[wid] = s1; lds[4 + wid] = s8; }
  __syncthreads();
  if (threadIdx.x == 0) {
    float t1 = lds[0] + lds[1] + lds[2] + lds[3];
    float t8 = lds[4] + lds[5] + lds[6] + lds[7];
    entpart[blockIdx.x]        = (double)(t1 * LN2F);
    entpart[2048 + blockIdx.x] = (double)(t8 * LN2F);
  }
}

// block per row: norm^2, w = 1/max(norm,eps), diag = norm2*w*w
__global__ void k_norms(const float* __restrict__ acts, float* __restrict__ wout,
                        float* __restrict__ diagout) {
  __shared__ float lds[4];
  int row = blockIdx.x;
  const float4* rp = (const float4*)(acts + (size_t)row * D_);
  int t = threadIdx.x;
  float s = 0.f;
#pragma unroll
  for (int j = 0; j < 4; ++j) {
    float4 v = rp[t + 256 * j];
    s += v.x * v.x + v.y * v.y + v.z * v.z + v.w * v.w;
  }
  s = wave_reduce_f(s);
  int wid = t >> 6;
  if ((t & 63) == 0) lds[wid] = s;
  __syncthreads();
  if (t == 0) {
    s = lds[0] + lds[1] + lds[2] + lds[3];
    float n = sqrtf(s);
    float w = 1.0f / fmaxf(n, EPSF);
    wout[row] = w;
    diagout[row] = s * w * w;
  }
}

// block = (class k, column chunk cc of 1024, row split); register accumulation only
__global__ void k_classsum(const float* __restrict__ acts, const int* __restrict__ counts,
                           const int* __restrict__ rowlist, const float* __restrict__ warr,
                           float* __restrict__ Cpart) {
  int bid = blockIdx.x;
  int k = bid & 63;
  int cc = (bid >> 6) & 3;
  int split = bid >> 8;  // 0..NSPLIT-1
  int cnt = counts[k];
  int beg = (cnt * split) / NSPLIT;
  int end = (cnt * (split + 1)) / NSPLIT;
  int t = threadIdx.x;
  int col = cc * 1024 + 4 * t;
  const int* rl = rowlist + k * B_;
  float4 acc = make_float4(0.f, 0.f, 0.f, 0.f);
#pragma unroll 2
  for (int r = beg; r < end; ++r) {
    int row = rl[r];
    float wv = warr[row];
    float4 v = *(const float4*)(acts + (size_t)row * D_ + col);
    acc.x += wv * v.x;
    acc.y += wv * v.y;
    acc.z += wv * v.z;
    acc.w += wv * v.w;
  }
  *(float4*)(Cpart + ((size_t)split * K_ + k) * D_ + col) = acc;
}

// mSm[k] = || sum_split Cpart[split][k][:] ||^2
__global__ void k_msm(const float* __restrict__ Cpart, float* __restrict__ mSm) {
  __shared__ float lds[4];
  int k = blockIdx.x;
  int t = threadIdx.x;
  float s = 0.f;
#pragma unroll
  for (int j = 0; j < D_ / 256; ++j) {
    size_t base = (size_t)k * D_ + t + 256 * j;
    float c = Cpart[base] + Cpart[(size_t)K_ * D_ + base] + Cpart[2ull * K_ * D_ + base] +
              Cpart[3ull * K_ * D_ + base];
    s += c * c;
  }
  s = wave_reduce_f(s);
  int wid = t >> 6;
  if ((t & 63) == 0) lds[wid] = s;
  __syncthreads();
  if (t == 0) mSm[k] = lds[0] + lds[1] + lds[2] + lds[3];
}

__global__ void k_final(const double* __restrict__ entpart, const int* __restrict__ labels,
                        const int* __restrict__ counts, const float* __restrict__ diag1,
                        const float* __restrict__ diag8, const float* __restrict__ mSm1,
                        const float* __restrict__ mSm8, float* __restrict__ out) {
  __shared__ float sd1[K_], sd8[K_];
  __shared__ double dl[8];
  int t = threadIdx.x;
  if (t < K_) { sd1[t] = 0.f; sd8[t] = 0.f; }
  __syncthreads();
  for (int r = t; r < B_; r += 256) {
    int k = labels[r];
    atomicAdd(&sd1[k], diag1[r]);
    atomicAdd(&sd8[k], diag8[r]);
  }
  double e1 = 0.0, e8 = 0.0;
  for (int i = t; i < 2048; i += 256) {
    e1 += entpart[i];
    e8 += entpart[2048 + i];
  }
#pragma unroll
  for (int o = 32; o > 0; o >>= 1) {
    e1 += __shfl_down(e1, o);
    e8 += __shfl_down(e8, o);
  }
  int wid = t >> 6;
  if ((t & 63) == 0) { dl[wid] = e1; dl[4 + wid] = e8; }
  __syncthreads();  // covers sd atomics and dl stores
  float pcm1 = 0.f, pcm8 = 0.f, valid = 0.f;
  if (t < K_) {
    float n = (float)counts[t];
    bool v = (n >= 2.0f);
    float np = fmaxf(0.5f * n * (n - 1.0f), 1.0f);
    valid = v ? 1.0f : 0.f;
    pcm1 = v ? 0.5f * (mSm1[t] - sd1[t]) / np : 0.f;
    pcm8 = v ? 0.5f * (mSm8[t] - sd8[t]) / np : 0.f;
  }
#pragma unroll
  for (int o = 32; o > 0; o >>= 1) {
    pcm1 += __shfl_down(pcm1, o);
    pcm8 += __shfl_down(pcm8, o);
    valid += __shfl_down(valid, o);
  }
  if (t == 0) {
    double etot1 = dl[0] + dl[1] + dl[2] + dl[3];
    double etot8 = dl[4] + dl[5] + dl[6] + dl[7];
    float sp1 = (float)(etot1 / (double)((long long)B_ * D_));
    float sp8 = (float)(etot8 / (double)((long long)B_ * D_));
    float cs1 = (valid > 0.f) ? pcm1 / fmaxf(valid, 1.0f) : 0.f;
    float cs8 = (valid > 0.f) ? pcm8 / fmaxf(valid, 1.0f) : 0.f;
    float sim1 = -cs1, sim8 = -cs8;
    out[0] = sim1 + sim8 + 0.001f * (sp1 + sp8);
    out[1] = sim1;
    out[2] = sim8;
    out[3] = sp1;
    out[4] = sp8;
  }
}

// ---------------- launcher ----------------
// ws layout (bytes):
//   0        : double entpart[2][2048]   (32768)
//   32768    : int    labels[B]          (32768)
//   65536    : int    counts[K]          (256)
//   65792    : float  mSm[2][K]          (512)
//   66560    : float  warr[2][B]         (65536)
//   132096   : float  diag[2][B]         (65536)
//   197632   : int    rowlist[K][B]      (2097152)
//   2294784  : float  Cpart[4][K][D]     (4194304)
//   total ~6.5 MB

extern "C" void kernel_launch(void* const* d_in, const int* in_sizes, int n_in,
                              void* d_out, int out_size, void* d_ws, size_t ws_size,
                              hipStream_t stream) {
  const float* probs = (const float*)d_in[0];
  const float* a1 = (const float*)d_in[1];
  const float* a8 = (const float*)d_in[2];
  const float* m1 = (const float*)d_in[3];
  const float* m8 = (const float*)d_in[4];
  float* out = (float*)d_out;
  char* ws = (char*)d_ws;

  double* entpart = (double*)(ws + 0);
  int* labels = (int*)(ws + 32768);
  int* counts = (int*)(ws + 65536);
  float* mSm = (float*)(ws + 65792);
  float* warr = (float*)(ws + 66560);
  float* diag = (float*)(ws + 132096);
  int* rowlist = (int*)(ws + 197632);
  float* Cpart = (float*)(ws + 2294784);

  k_init<<<1, 64, 0, stream>>>(counts);
  k_labels<<<B_ / 4, 256, 0, stream>>>(probs, labels, counts, rowlist);
  // masks first so they don't evict acts from L3 later
  k_entropy<<<2048, 256, 0, stream>>>((const float4*)m1, (const float4*)m8, entpart);
  // acts_1b: norms then immediate re-read (L3-resident) for class sums
  k_norms<<<B_, 256, 0, stream>>>(a1, warr, diag);
  k_classsum<<<K_ * 4 * NSPLIT, 256, 0, stream>>>(a1, counts, rowlist, warr, Cpart);
  k_msm<<<K_, 256, 0, stream>>>(Cpart, mSm);
  // acts_8b
  k_norms<<<B_, 256, 0, stream>>>(a8, warr + B_, diag + B_);
  k_classsum<<<K_ * 4 * NSPLIT, 256, 0, stream>>>(a8, counts, rowlist, warr + B_, Cpart);
  k_msm<<<K_, 256, 0, stream>>>(Cpart, mSm + K_);
  k_final<<<1, 256, 0, stream>>>(entpart, labels, counts, diag, diag + B_, mSm, mSm + K_, out);
}

// Round 3
// 206.443 us; speedup vs baseline: 1.0559x; 1.0559x over previous
//
#include <hip/hip_runtime.h>
#include <math.h>

#define B_ 8192
#define D_ 4096
#define K_ 64
#define EPSF 1e-8f
#define NSPLIT 4
#define LN2F 0.69314718056f

#define ENT_GRID 2048
#define ENT_BLOCK 256

typedef float f32x4 __attribute__((ext_vector_type(4)));

// ---------------- reduction helpers ----------------

__device__ __forceinline__ float wave_reduce_f(float v) {
#pragma unroll
  for (int o = 32; o > 0; o >>= 1) v += __shfl_down(v, o);
  return v;
}

// ---------------- kernels ----------------

__global__ void k_init(int* __restrict__ counts) {
  if (threadIdx.x < K_) counts[threadIdx.x] = 0;
}

// one wave per row; K_ == 64 == wavefront size, so one coalesced read + ballot
__global__ void k_labels(const float* __restrict__ probs, int* __restrict__ labels,
                         int* __restrict__ counts, int* __restrict__ rowlist) {
  int row = blockIdx.x * 4 + (threadIdx.x >> 6);
  int lane = threadIdx.x & 63;
  float p = probs[(size_t)row * K_ + lane];
  unsigned long long m = __ballot(p > 0.5f);
  if (lane == 0) {
    int k = __ffsll(m) - 1;
    if (k >= 0) {
      labels[row] = k;
      int pos = atomicAdd(&counts[k], 1);
      rowlist[k * B_ + pos] = row;
    }
  }
}

__device__ __forceinline__ float ent1(float p) {
  // -(p*log2(p) + q*log2(q)); caller multiplies by ln2
  p = fminf(fmaxf(p, EPSF), 1.0f - EPSF);
  float q = 1.0f - p;
  float lp = __builtin_amdgcn_logf(p);                   // v_log_f32: log2
  float lq = __builtin_amdgcn_logf(fmaxf(q, 1e-38f));
  return -(p * lp + q * lq);
}

__device__ __forceinline__ float ent4(f32x4 v) {
  return ent1(v.x) + ent1(v.y) + ent1(v.z) + ent1(v.w);
}

// fused binary entropy over both masks; ILP-8 nontemporal loads; per-block partials in double
__global__ __launch_bounds__(ENT_BLOCK) void k_entropy(const f32x4* __restrict__ m1,
                                                       const f32x4* __restrict__ m8,
                                                       double* __restrict__ entpart) {
  __shared__ float lds[8];
  const int NTH = ENT_GRID * ENT_BLOCK;  // 524288 threads; N4/NTH = 16 f32x4 each per mask
  int tid = blockIdx.x * ENT_BLOCK + threadIdx.x;
  float s1 = 0.f, s8 = 0.f;
#pragma unroll
  for (int o = 0; o < 4; ++o) {
    f32x4 a[4], b[4];
#pragma unroll
    for (int j = 0; j < 4; ++j) {
      int idx = tid + (o * 4 + j) * NTH;  // each load: wave reads 1KB contiguous
      a[j] = __builtin_nontemporal_load(&m1[idx]);
      b[j] = __builtin_nontemporal_load(&m8[idx]);
    }
#pragma unroll
    for (int j = 0; j < 4; ++j) {
      s1 += ent4(a[j]);
      s8 += ent4(b[j]);
    }
  }
  s1 = wave_reduce_f(s1);
  s8 = wave_reduce_f(s8);
  int wid = threadIdx.x >> 6;
  if ((threadIdx.x & 63) == 0) { lds[wid] = s1; lds[4 + wid] = s8; }
  __syncthreads();
  if (threadIdx.x == 0) {
    float t1 = lds[0] + lds[1] + lds[2] + lds[3];
    float t8 = lds[4] + lds[5] + lds[6] + lds[7];
    entpart[blockIdx.x]            = (double)(t1 * LN2F);
    entpart[ENT_GRID + blockIdx.x] = (double)(t8 * LN2F);
  }
}

// block per row: norm^2, w = 1/max(norm,eps), diag = norm2*w*w
__global__ __launch_bounds__(256) void k_norms(const float* __restrict__ acts,
                                               float* __restrict__ wout,
                                               float* __restrict__ diagout) {
  __shared__ float lds[4];
  int row = blockIdx.x;
  const float4* rp = (const float4*)(acts + (size_t)row * D_);
  int t = threadIdx.x;
  float4 v0 = rp[t];
  float4 v1 = rp[t + 256];
  float4 v2 = rp[t + 512];
  float4 v3 = rp[t + 768];
  float s = v0.x * v0.x + v0.y * v0.y + v0.z * v0.z + v0.w * v0.w;
  s += v1.x * v1.x + v1.y * v1.y + v1.z * v1.z + v1.w * v1.w;
  s += v2.x * v2.x + v2.y * v2.y + v2.z * v2.z + v2.w * v2.w;
  s += v3.x * v3.x + v3.y * v3.y + v3.z * v3.z + v3.w * v3.w;
  s = wave_reduce_f(s);
  int wid = t >> 6;
  if ((t & 63) == 0) lds[wid] = s;
  __syncthreads();
  if (t == 0) {
    s = lds[0] + lds[1] + lds[2] + lds[3];
    float n = sqrtf(s);
    float w = 1.0f / fmaxf(n, EPSF);
    wout[row] = w;
    diagout[row] = s * w * w;
  }
}

// block = (class k, column chunk cc of 1024, row split); register accumulation only
__global__ __launch_bounds__(256) void k_classsum(const float* __restrict__ acts,
                                                  const int* __restrict__ counts,
                                                  const int* __restrict__ rowlist,
                                                  const float* __restrict__ warr,
                                                  float* __restrict__ Cpart) {
  int bid = blockIdx.x;
  int k = bid & 63;
  int cc = (bid >> 6) & 3;
  int split = bid >> 8;  // 0..NSPLIT-1
  int cnt = counts[k];
  int beg = (cnt * split) / NSPLIT;
  int end = (cnt * (split + 1)) / NSPLIT;
  int t = threadIdx.x;
  int col = cc * 1024 + 4 * t;
  const int* rl = rowlist + k * B_;
  float4 acc0 = make_float4(0.f, 0.f, 0.f, 0.f);
  float4 acc1 = make_float4(0.f, 0.f, 0.f, 0.f);
  int r = beg;
  for (; r + 2 <= end; r += 2) {
    int row0 = rl[r];
    int row1 = rl[r + 1];
    float w0 = warr[row0];
    float w1 = warr[row1];
    float4 v0 = *(const float4*)(acts + (size_t)row0 * D_ + col);
    float4 v1 = *(const float4*)(acts + (size_t)row1 * D_ + col);
    acc0.x += w0 * v0.x; acc0.y += w0 * v0.y; acc0.z += w0 * v0.z; acc0.w += w0 * v0.w;
    acc1.x += w1 * v1.x; acc1.y += w1 * v1.y; acc1.z += w1 * v1.z; acc1.w += w1 * v1.w;
  }
  if (r < end) {
    int row0 = rl[r];
    float w0 = warr[row0];
    float4 v0 = *(const float4*)(acts + (size_t)row0 * D_ + col);
    acc0.x += w0 * v0.x; acc0.y += w0 * v0.y; acc0.z += w0 * v0.z; acc0.w += w0 * v0.w;
  }
  acc0.x += acc1.x; acc0.y += acc1.y; acc0.z += acc1.z; acc0.w += acc1.w;
  *(float4*)(Cpart + ((size_t)split * K_ + k) * D_ + col) = acc0;
}

// mSm[k] = || sum_split Cpart[split][k][:] ||^2
__global__ void k_msm(const float* __restrict__ Cpart, float* __restrict__ mSm) {
  __shared__ float lds[4];
  int k = blockIdx.x;
  int t = threadIdx.x;
  float s = 0.f;
#pragma unroll
  for (int j = 0; j < D_ / 256; ++j) {
    size_t base = (size_t)k * D_ + t + 256 * j;
    float c = Cpart[base] + Cpart[(size_t)K_ * D_ + base] + Cpart[2ull * K_ * D_ + base] +
              Cpart[3ull * K_ * D_ + base];
    s += c * c;
  }
  s = wave_reduce_f(s);
  int wid = t >> 6;
  if ((t & 63) == 0) lds[wid] = s;
  __syncthreads();
  if (t == 0) mSm[k] = lds[0] + lds[1] + lds[2] + lds[3];
}

__global__ void k_final(const double* __restrict__ entpart, const int* __restrict__ labels,
                        const int* __restrict__ counts, const float* __restrict__ diag1,
                        const float* __restrict__ diag8, const float* __restrict__ mSm1,
                        const float* __restrict__ mSm8, float* __restrict__ out) {
  __shared__ float sd1[K_], sd8[K_];
  __shared__ double dl[8];
  int t = threadIdx.x;
  if (t < K_) { sd1[t] = 0.f; sd8[t] = 0.f; }
  __syncthreads();
  for (int r = t; r < B_; r += 256) {
    int k = labels[r];
    atomicAdd(&sd1[k], diag1[r]);
    atomicAdd(&sd8[k], diag8[r]);
  }
  double e1 = 0.0, e8 = 0.0;
  for (int i = t; i < 2048; i += 256) {
    e1 += entpart[i];
    e8 += entpart[2048 + i];
  }
#pragma unroll
  for (int o = 32; o > 0; o >>= 1) {
    e1 += __shfl_down(e1, o);
    e8 += __shfl_down(e8, o);
  }
  int wid = t >> 6;
  if ((t & 63) == 0) { dl[wid] = e1; dl[4 + wid] = e8; }
  __syncthreads();  // covers sd atomics and dl stores
  float pcm1 = 0.f, pcm8 = 0.f, valid = 0.f;
  if (t < K_) {
    float n = (float)counts[t];
    bool v = (n >= 2.0f);
    float np = fmaxf(0.5f * n * (n - 1.0f), 1.0f);
    valid = v ? 1.0f : 0.f;
    pcm1 = v ? 0.5f * (mSm1[t] - sd1[t]) / np : 0.f;
    pcm8 = v ? 0.5f * (mSm8[t] - sd8[t]) / np : 0.f;
  }
#pragma unroll
  for (int o = 32; o > 0; o >>= 1) {
    pcm1 += __shfl_down(pcm1, o);
    pcm8 += __shfl_down(pcm8, o);
    valid += __shfl_down(valid, o);
  }
  if (t == 0) {
    double etot1 = dl[0] + dl[1] + dl[2] + dl[3];
    double etot8 = dl[4] + dl[5] + dl[6] + dl[7];
    float sp1 = (float)(etot1 / (double)((long long)B_ * D_));
    float sp8 = (float)(etot8 / (double)((long long)B_ * D_));
    float cs1 = (valid > 0.f) ? pcm1 / fmaxf(valid, 1.0f) : 0.f;
    float cs8 = (valid > 0.f) ? pcm8 / fmaxf(valid, 1.0f) : 0.f;
    float sim1 = -cs1, sim8 = -cs8;
    out[0] = sim1 + sim8 + 0.001f * (sp1 + sp8);
    out[1] = sim1;
    out[2] = sim8;
    out[3] = sp1;
    out[4] = sp8;
  }
}

// ---------------- launcher ----------------
// ws layout (bytes):
//   0        : double entpart[2][2048]   (32768)
//   32768    : int    labels[B]          (32768)
//   65536    : int    counts[K]          (256)
//   65792    : float  mSm[2][K]          (512)
//   66560    : float  warr[2][B]         (65536)
//   132096   : float  diag[2][B]         (65536)
//   197632   : int    rowlist[K][B]      (2097152)
//   2294784  : float  Cpart[4][K][D]     (4194304)
//   total ~6.5 MB

extern "C" void kernel_launch(void* const* d_in, const int* in_sizes, int n_in,
                              void* d_out, int out_size, void* d_ws, size_t ws_size,
                              hipStream_t stream) {
  const float* probs = (const float*)d_in[0];
  const float* a1 = (const float*)d_in[1];
  const float* a8 = (const float*)d_in[2];
  const float* m1 = (const float*)d_in[3];
  const float* m8 = (const float*)d_in[4];
  float* out = (float*)d_out;
  char* ws = (char*)d_ws;

  double* entpart = (double*)(ws + 0);
  int* labels = (int*)(ws + 32768);
  int* counts = (int*)(ws + 65536);
  float* mSm = (float*)(ws + 65792);
  float* warr = (float*)(ws + 66560);
  float* diag = (float*)(ws + 132096);
  int* rowlist = (int*)(ws + 197632);
  float* Cpart = (float*)(ws + 2294784);

  k_init<<<1, 64, 0, stream>>>(counts);
  k_labels<<<B_ / 4, 256, 0, stream>>>(probs, labels, counts, rowlist);
  // masks first (nontemporal — don't evict acts from L3)
  k_entropy<<<ENT_GRID, ENT_BLOCK, 0, stream>>>((const f32x4*)m1, (const f32x4*)m8, entpart);
  // acts_1b: norms then immediate re-read (L3-resident) for class sums
  k_norms<<<B_, 256, 0, stream>>>(a1, warr, diag);
  k_classsum<<<K_ * 4 * NSPLIT, 256, 0, stream>>>(a1, counts, rowlist, warr, Cpart);
  k_msm<<<K_, 256, 0, stream>>>(Cpart, mSm);
  // acts_8b
  k_norms<<<B_, 256, 0, stream>>>(a8, warr + B_, diag + B_);
  k_classsum<<<K_ * 4 * NSPLIT, 256, 0, stream>>>(a8, counts, rowlist, warr + B_, Cpart);
  k_msm<<<K_, 256, 0, stream>>>(Cpart, mSm + K_);
  k_final<<<1, 256, 0, stream>>>(entpart, labels, counts, diag, diag + B_, mSm, mSm + K_, out);
}